// Round 14
// baseline (713.307 us; speedup 1.0000x reference)
//
#include <hip/hip_runtime.h>
#include <hip/hip_bf16.h>
#include <cstdint>

// ---------------------------------------------------------------------------
// FullModel: hetero-GraphSAGE (2 layers) + 3 MLP heads.
// R14 = R13 with the nontemporal-store builtin fixed (use clang ext-vector
// f32x4, not HIP_vector_type float4). NT stores on write-once outputs
// (out_cat/out_sku/out_emb/out_churn) -> bypass L2, keep it for read streams.
// All GEMMs: mfma_f32_16x16x32_bf16, fp32 acc, global_load_lds(16B) staging,
// both-sides XOR swizzle (G21). MFMA kernels: __launch_bounds__(256,4).
// ---------------------------------------------------------------------------

typedef __attribute__((ext_vector_type(8))) short bf16x8;
typedef __attribute__((ext_vector_type(4))) float f32x4;

__device__ __forceinline__ float b2f(unsigned short u) {
  return __uint_as_float(((unsigned)u) << 16);
}
__device__ __forceinline__ unsigned short f2b(float f) {
  unsigned u = __float_as_uint(f);
  return (unsigned short)((u + 0x7FFFu + ((u >> 16) & 1u)) >> 16);
}
__device__ __forceinline__ float sigmoidf_(float v) {
  return 1.0f / (1.0f + __expf(-v));
}
__device__ __forceinline__ void nt_store4(float* p, f32x4 v) {
  __builtin_nontemporal_store(v, (f32x4*)p);
}
__device__ __forceinline__ void nt_store1(float* p, float v) {
  __builtin_nontemporal_store(v, p);
}

__device__ __forceinline__ float waveReduceSum(float v) {
  #pragma unroll
  for (int s = 32; s > 0; s >>= 1) v += __shfl_xor(v, s, 64);
  return v;
}

__device__ __forceinline__ void gload16(const void* g, void* l) {
  __builtin_amdgcn_global_load_lds(
      (const __attribute__((address_space(1))) unsigned int*)g,
      (__attribute__((address_space(3))) unsigned int*)l, 16, 0, 0);
}

// stage a [128 rows][32 k] bf16 tile (linear LDS dest, pre-swizzled source)
__device__ __forceinline__ void stage_tile(const unsigned short* __restrict__ G,
                                           int ld, unsigned short* lds,
                                           int wave, int lane) {
  #pragma unroll
  for (int j = 0; j < 2; ++j) {
    const int p = wave * 128 + j * 64 + lane;
    const int rr = p >> 2;
    const int sl = (p & 3) ^ (rr & 3);
    gload16(G + (size_t)rr * ld + (sl << 3), lds + ((wave * 128 + j * 64) << 3));
  }
}

// stage a [128 rows][128 k] bf16 tile (2048 16B-slots, 8 per thread)
__device__ __forceinline__ void stage_tile128(const unsigned short* __restrict__ G,
                                              int ldg, unsigned short* lds,
                                              int wave, int lane) {
  #pragma unroll
  for (int u = 0; u < 8; ++u) {
    const int base = u * 256 + wave * 64;
    const int p = base + lane;
    const int row = p >> 4;
    const int sl = (p & 15) ^ (row & 7);
    gload16(G + (size_t)row * ldg + (sl << 3), lds + (base << 3));
  }
}

// read an 8-elem bf16 fragment from a staged [rows][32] tile
__device__ __forceinline__ bf16x8 read_frag32(const unsigned short* lds, int row, int kg) {
  const int srd = kg ^ (row & 3);
  return *(const bf16x8*)&lds[row * 32 + (srd << 3)];
}

// [128][128] bf16 LDS tile, 16B-slot swizzle: phys = logical ^ (row&7)
__device__ __forceinline__ bf16x8 read_frag128(const unsigned short* lds, int row, int kslot) {
  const int ps = kslot ^ (row & 7);
  return *(const bf16x8*)&lds[row * 128 + (ps << 3)];
}
__device__ __forceinline__ void write_elem128(unsigned short* lds, int row, int col,
                                              unsigned short v) {
  const int slot = (col >> 3) ^ (row & 7);
  lds[row * 128 + (slot << 3) + (col & 7)] = v;
}

// direct global fragment: 16B at row*ld + koff (L2-hot weights only)
__device__ __forceinline__ bf16x8 gfrag(const unsigned short* __restrict__ G,
                                        int row, int ld, int koff) {
  return *(const bf16x8*)&G[(size_t)row * ld + koff];
}

// ---- k_front: weight prep (blocks [0,512)) + l2norm + histogram ----
__global__ void k_front(
    const float* __restrict__ W1l_cs, const float* __restrict__ W1r_cs,
    const float* __restrict__ Wlin1_s, const float* __restrict__ b1_cs,
    const float* __restrict__ blin1_s,
    const float* __restrict__ W1l_sc, const float* __restrict__ W1r_sc,
    const float* __restrict__ Wlin1_c, const float* __restrict__ b1_sc,
    const float* __restrict__ blin1_c,
    const float* __restrict__ W2l_sc, const float* __restrict__ W2r_sc,
    const float* __restrict__ Wlin2_c, const float* __restrict__ b2_sc,
    const float* __restrict__ blin2_c,
    const float* __restrict__ Wch1, const float* __restrict__ bch1,
    const float* __restrict__ Wcat1, const float* __restrict__ bcat1,
    const float* __restrict__ Wsk1, const float* __restrict__ bsk1,
    const float* __restrict__ Wcat2, const float* __restrict__ Wsk2,
    unsigned short* __restrict__ wc1s, float* __restrict__ bc1s,
    unsigned short* __restrict__ wc1c, float* __restrict__ bc1c,
    unsigned short* __restrict__ wc2c, float* __restrict__ bc2c,
    unsigned short* __restrict__ whh, float* __restrict__ bhh,
    unsigned short* __restrict__ wcat2p, unsigned short* __restrict__ wsk2p,
    int NCAT, int NCATp, int NSKU, int NSKUp,
    const float* __restrict__ xc, const float* __restrict__ xs,
    unsigned short* __restrict__ concat_c, unsigned short* __restrict__ concat_s,
    int Nc, int Ns, int nl2,
    const int* __restrict__ cs_dst, const int* __restrict__ sc_dst,
    int* __restrict__ cnt, int E) {
  const int blk = blockIdx.x;
  if (blk < 512) {
    const int i = blk * 256 + threadIdx.x;
    if (i < 65536) {
      {
        int n = i >> 8, k = i & 255;
        wc1s[i] = f2b(k < 128 ? W1l_cs[n * 128 + k]
                              : W1r_cs[n * 128 + k - 128] + Wlin1_s[n * 128 + k - 128]);
        wc1c[i] = f2b(k < 128 ? W1l_sc[n * 128 + k]
                              : W1r_sc[n * 128 + k - 128] + Wlin1_c[n * 128 + k - 128]);
      }
      {
        int n = i >> 9, k = i & 511;
        wc2c[i] = f2b(k < 256 ? W2l_sc[n * 256 + k]
                              : W2r_sc[n * 256 + k - 256] + Wlin2_c[n * 256 + k - 256]);
      }
    }
    if (i < 256) { bc1s[i] = b1_cs[i] + blin1_s[i]; bc1c[i] = b1_sc[i] + blin1_c[i]; }
    if (i < 128) bc2c[i] = b2_sc[i] + blin2_c[i];
    if (i < 384 * 128) {
      int n = i >> 7, k = i & 127;
      const float* w = n < 128 ? Wch1 : (n < 256 ? Wcat1 : Wsk1);
      whh[i] = f2b(w[(n & 127) * 128 + k]);
    }
    if (i < 384) bhh[i] = i < 128 ? bch1[i] : (i < 256 ? bcat1[i - 128] : bsk1[i - 256]);
    if (i < NCATp * 128) wcat2p[i] = (i >> 7) < NCAT ? f2b(Wcat2[i]) : (unsigned short)0;
    if (i < NSKUp * 128) wsk2p[i] = (i >> 7) < NSKU ? f2b(Wsk2[i]) : (unsigned short)0;
  } else if (blk < 512 + nl2) {
    const int wid = (blk - 512) * 4 + (threadIdx.x >> 6);
    const int lane = threadIdx.x & 63;
    const float* x;
    unsigned short* out;
    if (wid < Nc) {
      x = xc + (size_t)wid * 128;
      out = concat_c + (size_t)wid * 256 + 128;
    } else {
      int w = wid - Nc;
      if (w >= Ns) return;
      x = xs + (size_t)w * 128;
      out = concat_s + (size_t)w * 256 + 128;
    }
    const float2 v = *(const float2*)&x[lane * 2];
    float ss = waveReduceSum(v.x * v.x + v.y * v.y);
    float sc = 1.0f / fmaxf(sqrtf(ss), 1e-12f);
    out[lane * 2] = f2b(v.x * sc);
    out[lane * 2 + 1] = f2b(v.y * sc);
  } else {
    const int i = (blk - 512 - nl2) * 256 + threadIdx.x;
    if (i < E) atomicAdd(&cnt[cs_dst[i]], 1);
    else if (i < 2 * E) atomicAdd(&cnt[Ns + sc_dst[i - E]], 1);
  }
}

// ---- exclusive scan (3-dispatch) ----
__global__ void k_scan1(const int* __restrict__ in, int* __restrict__ out,
                        int* __restrict__ partials, int nin, int nout) {
  __shared__ int sd[256];
  const int tid = threadIdx.x;
  const int base = blockIdx.x * 2048 + tid * 8;
  int v[8];
  int tsum = 0;
  #pragma unroll
  for (int u = 0; u < 8; ++u) {
    int idx = base + u;
    int t = (idx < nin) ? in[idx] : 0;
    v[u] = tsum; tsum += t;
  }
  sd[tid] = tsum;
  __syncthreads();
  for (int offp = 1; offp < 256; offp <<= 1) {
    int t = (tid >= offp) ? sd[tid - offp] : 0;
    __syncthreads();
    sd[tid] += t;
    __syncthreads();
  }
  int texcl = (tid == 0) ? 0 : sd[tid - 1];
  if (tid == 255) partials[blockIdx.x] = sd[255];
  #pragma unroll
  for (int u = 0; u < 8; ++u) {
    int idx = base + u;
    if (idx < nout) out[idx] = v[u] + texcl;
  }
}

__global__ void k_scan2(int* __restrict__ partials, int nb) {
  __shared__ int sd[256];
  const int tid = threadIdx.x;
  int v = (tid < nb) ? partials[tid] : 0;
  sd[tid] = v;
  __syncthreads();
  for (int offp = 1; offp < 256; offp <<= 1) {
    int t = (tid >= offp) ? sd[tid - offp] : 0;
    __syncthreads();
    sd[tid] += t;
    __syncthreads();
  }
  if (tid < nb) partials[tid] = (tid == 0) ? 0 : sd[tid - 1];
}

__global__ void k_scan3(int* __restrict__ out, const int* __restrict__ partials, int nout) {
  int add = partials[blockIdx.x];
  int base = blockIdx.x * 2048 + threadIdx.x * 8;
  #pragma unroll
  for (int u = 0; u < 8; ++u) {
    int idx = base + u;
    if (idx < nout) out[idx] += add;
  }
}

// ---- scatter both edge sets into one adjacency array ----
__global__ void k_scatter_both(const int* __restrict__ cs_src, const int* __restrict__ cs_dst,
                               const int* __restrict__ sc_src, const int* __restrict__ sc_dst,
                               const int* __restrict__ off, int* __restrict__ cur,
                               int* __restrict__ lst, int E, int Ns) {
  int i = blockIdx.x * blockDim.x + threadIdx.x;
  if (i >= 2 * E) return;
  int d, s;
  if (i < E) { d = cs_dst[i]; s = cs_src[i]; }
  else { d = Ns + sc_dst[i - E]; s = sc_src[i - E]; }
  int p = atomicAdd(&cur[d], 1);
  lst[off[d] + p] = s;
}

// ---- layer-1 mean aggregation, both directions, depth-4 unrolled ----
__global__ void k_agg128_both(const unsigned short* __restrict__ concat_c,
                              const unsigned short* __restrict__ concat_s,
                              const int* __restrict__ off, const int* __restrict__ lst,
                              unsigned short* __restrict__ out_s,
                              unsigned short* __restrict__ out_c, int Ns, int Nc) {
  int wid = (blockIdx.x * blockDim.x + threadIdx.x) >> 6;
  int lane = threadIdx.x & 63;
  const unsigned short* feat;
  unsigned short* out;
  int s, e;
  if (wid < Ns) {
    s = off[wid]; e = off[wid + 1];
    feat = concat_c; out = out_s + (size_t)wid * 256;
  } else {
    int w = wid - Ns;
    if (w >= Nc) return;
    s = off[Ns + w]; e = off[Ns + w + 1];
    feat = concat_s; out = out_c + (size_t)w * 256;
  }
  float ax0 = 0.f, ay0 = 0.f, ax1 = 0.f, ay1 = 0.f;
  float ax2 = 0.f, ay2 = 0.f, ax3 = 0.f, ay3 = 0.f;
  int i = s;
  for (; i + 4 <= e; i += 4) {
    int r0 = lst[i], r1 = lst[i + 1], r2 = lst[i + 2], r3 = lst[i + 3];
    unsigned v0 = *(const unsigned*)&feat[(size_t)r0 * 256 + 128 + lane * 2];
    unsigned v1 = *(const unsigned*)&feat[(size_t)r1 * 256 + 128 + lane * 2];
    unsigned v2 = *(const unsigned*)&feat[(size_t)r2 * 256 + 128 + lane * 2];
    unsigned v3 = *(const unsigned*)&feat[(size_t)r3 * 256 + 128 + lane * 2];
    ax0 += b2f((unsigned short)(v0 & 0xFFFF)); ay0 += b2f((unsigned short)(v0 >> 16));
    ax1 += b2f((unsigned short)(v1 & 0xFFFF)); ay1 += b2f((unsigned short)(v1 >> 16));
    ax2 += b2f((unsigned short)(v2 & 0xFFFF)); ay2 += b2f((unsigned short)(v2 >> 16));
    ax3 += b2f((unsigned short)(v3 & 0xFFFF)); ay3 += b2f((unsigned short)(v3 >> 16));
  }
  for (; i < e; ++i) {
    int r0 = lst[i];
    unsigned v0 = *(const unsigned*)&feat[(size_t)r0 * 256 + 128 + lane * 2];
    ax0 += b2f((unsigned short)(v0 & 0xFFFF)); ay0 += b2f((unsigned short)(v0 >> 16));
  }
  float inv = 1.0f / (float)((e - s) > 0 ? (e - s) : 1);
  out[lane * 2] = f2b((ax0 + ax1 + ax2 + ax3) * inv);
  out[lane * 2 + 1] = f2b((ay0 + ay1 + ay2 + ay3) * inv);
}

// ---- layer-2 mean aggregation (256-wide), depth-4 unrolled ----
__global__ void k_agg_mean256(const unsigned short* __restrict__ feat,
                              const int* __restrict__ off, const int* __restrict__ lst,
                              unsigned short* __restrict__ out, int ostride, int n) {
  int wid = (blockIdx.x * blockDim.x + threadIdx.x) >> 6;
  int lane = threadIdx.x & 63;
  if (wid >= n) return;
  int s = off[wid], e = off[wid + 1];
  float a[4] = {0.f, 0.f, 0.f, 0.f};
  float b[4] = {0.f, 0.f, 0.f, 0.f};
  float c[4] = {0.f, 0.f, 0.f, 0.f};
  float d[4] = {0.f, 0.f, 0.f, 0.f};
  int i = s;
  for (; i + 4 <= e; i += 4) {
    int r0 = lst[i], r1 = lst[i + 1], r2 = lst[i + 2], r3 = lst[i + 3];
    uint2 v0 = *(const uint2*)&feat[(size_t)r0 * 256 + lane * 4];
    uint2 v1 = *(const uint2*)&feat[(size_t)r1 * 256 + lane * 4];
    uint2 v2 = *(const uint2*)&feat[(size_t)r2 * 256 + lane * 4];
    uint2 v3 = *(const uint2*)&feat[(size_t)r3 * 256 + lane * 4];
    a[0] += b2f((unsigned short)(v0.x & 0xFFFF)); a[1] += b2f((unsigned short)(v0.x >> 16));
    a[2] += b2f((unsigned short)(v0.y & 0xFFFF)); a[3] += b2f((unsigned short)(v0.y >> 16));
    b[0] += b2f((unsigned short)(v1.x & 0xFFFF)); b[1] += b2f((unsigned short)(v1.x >> 16));
    b[2] += b2f((unsigned short)(v1.y & 0xFFFF)); b[3] += b2f((unsigned short)(v1.y >> 16));
    c[0] += b2f((unsigned short)(v2.x & 0xFFFF)); c[1] += b2f((unsigned short)(v2.x >> 16));
    c[2] += b2f((unsigned short)(v2.y & 0xFFFF)); c[3] += b2f((unsigned short)(v2.y >> 16));
    d[0] += b2f((unsigned short)(v3.x & 0xFFFF)); d[1] += b2f((unsigned short)(v3.x >> 16));
    d[2] += b2f((unsigned short)(v3.y & 0xFFFF)); d[3] += b2f((unsigned short)(v3.y >> 16));
  }
  for (; i < e; ++i) {
    int r0 = lst[i];
    uint2 v0 = *(const uint2*)&feat[(size_t)r0 * 256 + lane * 4];
    a[0] += b2f((unsigned short)(v0.x & 0xFFFF)); a[1] += b2f((unsigned short)(v0.x >> 16));
    a[2] += b2f((unsigned short)(v0.y & 0xFFFF)); a[3] += b2f((unsigned short)(v0.y >> 16));
  }
  float inv = 1.0f / (float)((e - s) > 0 ? (e - s) : 1);
  unsigned short* o = &out[(size_t)wid * ostride + lane * 4];
  o[0] = f2b((a[0] + b[0] + c[0] + d[0]) * inv);
  o[1] = f2b((a[1] + b[1] + c[1] + d[1]) * inv);
  o[2] = f2b((a[2] + b[2] + c[2] + d[2]) * inv);
  o[3] = f2b((a[3] + b[3] + c[3] + d[3]) * inv);
}

// ---- layer-1 GEMMs, both node types, 2-phase pipelined staging ----
__global__ __launch_bounds__(256, 4) void k_gemm1_both(
    const unsigned short* __restrict__ As_g, const unsigned short* __restrict__ Ws_g,
    const float* __restrict__ bs_g, unsigned short* __restrict__ Cs_g, int Ms, int NTs2,
    const unsigned short* __restrict__ Ac_g, const unsigned short* __restrict__ Wc_g,
    const float* __restrict__ bc_g, unsigned short* __restrict__ Cc_g, int Mc) {
  __shared__ __align__(16) unsigned short As[8192];  // dbuf 2x4096
  __shared__ __align__(16) unsigned short Bs[8192];
  const int nwg = gridDim.x, orig = blockIdx.x;
  const int q8 = nwg >> 3, r8 = nwg & 7;
  const int xcd = orig & 7, cidx = orig >> 3;
  int wg = (xcd < r8 ? xcd * (q8 + 1) : r8 * (q8 + 1) + (xcd - r8) * q8) + cidx;

  const unsigned short *A, *W;
  const float* bias;
  unsigned short* C;
  int M, ldc;
  if (wg < NTs2) { A = As_g; W = Ws_g; bias = bs_g; C = Cs_g; M = Ms; ldc = 256; }
  else { wg -= NTs2; A = Ac_g; W = Wc_g; bias = bc_g; C = Cc_g; M = Mc; ldc = 512; }
  const int bm = (wg >> 1) * 128, bn = (wg & 1) * 128;

  const int tid = threadIdx.x, lane = tid & 63, wave = tid >> 6;
  const int wm = (wave >> 1) << 6, wn = (wave & 1) << 6;
  const int l15 = lane & 15, l4 = lane >> 4;

  const unsigned short* Abase = A + (size_t)bm * 256;
  const unsigned short* Wbase = W + (size_t)bn * 256;

  f32x4 acc[4][4] = {};
  stage_tile(Abase, 256, As, wave, lane);
  stage_tile(Wbase, 256, Bs, wave, lane);
  __syncthreads();
  int cur = 0;
  for (int t = 0; t < 8; ++t) {
    if (t < 7) {
      stage_tile(Abase + (t + 1) * 32, 256, As + ((cur ^ 1) << 12), wave, lane);
      stage_tile(Wbase + (t + 1) * 32, 256, Bs + ((cur ^ 1) << 12), wave, lane);
    }
    const unsigned short* Ac = As + (cur << 12);
    const unsigned short* Bc = Bs + (cur << 12);
    bf16x8 af[4], bfr[4];
    #pragma unroll
    for (int i = 0; i < 4; ++i) {
      af[i] = read_frag32(Ac, wm + i * 16 + l15, l4);
      bfr[i] = read_frag32(Bc, wn + i * 16 + l15, l4);
    }
    #pragma unroll
    for (int i = 0; i < 4; ++i)
      #pragma unroll
      for (int j = 0; j < 4; ++j)
        acc[i][j] = __builtin_amdgcn_mfma_f32_16x16x32_bf16(af[i], bfr[j], acc[i][j], 0, 0, 0);
    __syncthreads();
    cur ^= 1;
  }
  #pragma unroll
  for (int j = 0; j < 4; ++j) {
    int col = bn + wn + j * 16 + l15;
    float bj = bias[col];
    #pragma unroll
    for (int i = 0; i < 4; ++i) {
      int r0 = bm + wm + i * 16 + (l4 << 2);
      #pragma unroll
      for (int q = 0; q < 4; ++q) {
        int row = r0 + q;
        if (row < M) C[(size_t)row * ldc + col] = f2b(fmaxf(acc[i][j][q] + bj, 0.0f));
      }
    }
  }
}

// ---- k_embhid: emb (K=512, pipelined, 32 KB aliased LDS) -> out_emb fp32 +
//      embT LDS; then 12 barrier-free steps (Whh direct) -> hidden[Ncp][384] ----
__global__ __launch_bounds__(256, 4) void k_embhid(
    const unsigned short* __restrict__ A2, const unsigned short* __restrict__ W2,
    const float* __restrict__ b2,
    const unsigned short* __restrict__ Whh, const float* __restrict__ bhh,
    float* __restrict__ out_emb, unsigned short* __restrict__ hidden, int M) {
  __shared__ __align__(16) unsigned short smem[16384];  // 32 KB total
  unsigned short* As = smem;          // dbuf 2x4096 ushort (16 KB)
  unsigned short* Bs = smem + 8192;   // dbuf 2x4096 ushort (16 KB)
  unsigned short* embT = smem;        // [128][128] alias, valid after emb loop

  const int bm = blockIdx.x * 128;
  const int tid = threadIdx.x, lane = tid & 63, wave = tid >> 6;
  const int wm = (wave >> 1) << 6, wn = (wave & 1) << 6;
  const int l15 = lane & 15, l4 = lane >> 4;

  f32x4 acc[4][4] = {};
  {  // emb: K=512, 16 pipelined steps
    const unsigned short* Abase = A2 + (size_t)bm * 512;
    stage_tile(Abase, 512, As, wave, lane);
    stage_tile(W2, 512, Bs, wave, lane);
    __syncthreads();
    int cur = 0;
    for (int t = 0; t < 16; ++t) {
      if (t < 15) {
        stage_tile(Abase + (t + 1) * 32, 512, As + ((cur ^ 1) << 12), wave, lane);
        stage_tile(W2 + (t + 1) * 32, 512, Bs + ((cur ^ 1) << 12), wave, lane);
      }
      const unsigned short* Ac = As + (cur << 12);
      const unsigned short* Bc = Bs + (cur << 12);
      bf16x8 af[4], bfr[4];
      #pragma unroll
      for (int i = 0; i < 4; ++i) {
        af[i] = read_frag32(Ac, wm + i * 16 + l15, l4);
        bfr[i] = read_frag32(Bc, wn + i * 16 + l15, l4);
      }
      #pragma unroll
      for (int i = 0; i < 4; ++i)
        #pragma unroll
        for (int j = 0; j < 4; ++j)
          acc[i][j] = __builtin_amdgcn_mfma_f32_16x16x32_bf16(af[i], bfr[j], acc[i][j], 0, 0, 0);
      __syncthreads();  // after final iter: all LDS reads done -> embT alias safe
      cur ^= 1;
    }
    #pragma unroll
    for (int j = 0; j < 4; ++j) {
      int col = wn + j * 16 + l15;
      float bj = b2[col];
      #pragma unroll
      for (int i = 0; i < 4; ++i) {
        int r0 = wm + i * 16 + (l4 << 2);
        #pragma unroll
        for (int q = 0; q < 4; ++q) {
          float v = acc[i][j][q] + bj;
          int rl = r0 + q;
          if (bm + rl < M) nt_store1(&out_emb[(size_t)(bm + rl) * 128 + col], v);
          write_elem128(embT, rl, col, f2b(v));
        }
      }
    }
  }
  __syncthreads();  // embT visible to all waves

  // hidden: 12 flat steps (hc = s>>2, tt = s&3), Whh direct-global, no barriers
  f32x4 hacc[4][4] = {};
  for (int s = 0; s < 12; ++s) {
    const int hc = s >> 2, tt = s & 3;
    bf16x8 af[4], bfr[4];
    const int kslot = tt * 4 + l4;
    #pragma unroll
    for (int i = 0; i < 4; ++i) {
      af[i] = read_frag128(embT, wm + i * 16 + l15, kslot);
      bfr[i] = gfrag(Whh, hc * 128 + wn + i * 16 + l15, 128, tt * 32 + l4 * 8);
    }
    #pragma unroll
    for (int i = 0; i < 4; ++i)
      #pragma unroll
      for (int j = 0; j < 4; ++j)
        hacc[i][j] = __builtin_amdgcn_mfma_f32_16x16x32_bf16(af[i], bfr[j], hacc[i][j], 0, 0, 0);
    if (tt == 3) {  // epilogue for this chunk
      #pragma unroll
      for (int j = 0; j < 4; ++j) {
        int col = wn + j * 16 + l15;
        float bj = bhh[hc * 128 + col];
        #pragma unroll
        for (int i = 0; i < 4; ++i) {
          int r0 = wm + i * 16 + (l4 << 2);
          #pragma unroll
          for (int q = 0; q < 4; ++q) {
            hidden[(size_t)(bm + r0 + q) * 384 + hc * 128 + col] =
                f2b(fmaxf(hacc[i][j][q] + bj, 0.0f));
            hacc[i][j][q] = 0.0f;
          }
        }
      }
    }
  }
}

// ---- k_heads: one 128x128 chunk per block (R8 shape); hidden staged in LDS,
//      W chunk direct (L2-hot); churn role last. NT float4 output stores. ----
__global__ __launch_bounds__(256, 4) void k_heads(
    const unsigned short* __restrict__ hidden,
    const unsigned short* __restrict__ Wcat, const float* __restrict__ bcat, int NCAT,
    int ncat_ch,
    const unsigned short* __restrict__ Wsku, const float* __restrict__ bsku, int NSKU,
    int nsku_ch,
    const float* __restrict__ wch2, const float* __restrict__ bch2,
    float* __restrict__ out_cat, float* __restrict__ out_sku,
    float* __restrict__ out_churn, int M) {
  __shared__ __align__(16) unsigned short Bh[16384];  // hidden tile [128][128]

  const int nwg = gridDim.x, orig = blockIdx.x;
  const int q8 = nwg >> 3, r8 = nwg & 7;
  const int xcd = orig & 7, cidx = orig >> 3;
  const int wg = (xcd < r8 ? xcd * (q8 + 1) : r8 * (q8 + 1) + (xcd - r8) * q8) + cidx;

  const int nroles = ncat_ch + nsku_ch + 1;
  const int bt = wg / nroles;
  const int c = wg % nroles;
  const int bm = bt * 128;

  const int tid = threadIdx.x, lane = tid & 63, wave = tid >> 6;

  if (c == ncat_ch + nsku_ch) {
    const float2 ww = *(const float2*)&wch2[lane * 2];
    const float bb = bch2[0];
    for (int r = wave * 32; r < wave * 32 + 32; ++r) {
      const int row = bm + r;
      if (row >= M) break;
      unsigned v = *(const unsigned*)&hidden[(size_t)row * 384 + lane * 2];
      float sum = waveReduceSum(b2f((unsigned short)(v & 0xFFFF)) * ww.x +
                                b2f((unsigned short)(v >> 16)) * ww.y);
      if (lane == 0) nt_store1(&out_churn[row], sigmoidf_(sum + bb));
    }
    return;
  }

  const unsigned short* Wh;
  const float* bh;
  float* oh;
  int Nh, cc, hoff;
  if (c < ncat_ch) { Wh = Wcat; bh = bcat; oh = out_cat; Nh = NCAT; cc = c; hoff = 128; }
  else { Wh = Wsku; bh = bsku; oh = out_sku; Nh = NSKU; cc = c - ncat_ch; hoff = 256; }

  const int wm = (wave >> 1) << 6, wn = (wave & 1) << 6;
  const int l15 = lane & 15, l4 = lane >> 4;

  stage_tile128(hidden + (size_t)bm * 384 + hoff, 384, Bh, wave, lane);
  __syncthreads();

  f32x4 acc[4][4] = {};
  #pragma unroll
  for (int ks = 0; ks < 4; ++ks) {
    bf16x8 af[4], bfr[4];
    #pragma unroll
    for (int i = 0; i < 4; ++i) {
      af[i] = gfrag(Wh, cc * 128 + wm + i * 16 + l15, 128, ks * 32 + l4 * 8);
      bfr[i] = read_frag128(Bh, wn + i * 16 + l15, ks * 4 + l4);
    }
    #pragma unroll
    for (int i = 0; i < 4; ++i)
      #pragma unroll
      for (int j = 0; j < 4; ++j)
        acc[i][j] = __builtin_amdgcn_mfma_f32_16x16x32_bf16(af[i], bfr[j], acc[i][j], 0, 0, 0);
  }

  // transposed epilogue: D[a=headcol][b=client row], NT stores
  #pragma unroll
  for (int i = 0; i < 4; ++i) {
    const int n0 = cc * 128 + wm + i * 16 + (l4 << 2);
    if (n0 < Nh) {  // Nh % 4 == 0 -> whole quad valid
      const float4 bv = *(const float4*)&bh[n0];
      #pragma unroll
      for (int j = 0; j < 4; ++j) {
        const int m = wn + j * 16 + l15;
        if (bm + m < M) {
          f32x4 ov;
          ov.x = sigmoidf_(acc[i][j][0] + bv.x);
          ov.y = sigmoidf_(acc[i][j][1] + bv.y);
          ov.z = sigmoidf_(acc[i][j][2] + bv.z);
          ov.w = sigmoidf_(acc[i][j][3] + bv.w);
          nt_store4(&oh[(size_t)(bm + m) * Nh + n0], ov);
        }
      }
    }
  }
}

extern "C" void kernel_launch(void* const* d_in, const int* in_sizes, int n_in,
                              void* d_out, int out_size, void* d_ws, size_t ws_size,
                              hipStream_t stream) {
  const float* x_client = (const float*)d_in[0];
  const float* x_sku    = (const float*)d_in[1];
  const int* cs_src = (const int*)d_in[2];
  const int* cs_dst = (const int*)d_in[3];
  const int* sc_src = (const int*)d_in[4];
  const int* sc_dst = (const int*)d_in[5];
  const float* W1l_cs = (const float*)d_in[6];
  const float* b1_cs  = (const float*)d_in[7];
  const float* W1r_cs = (const float*)d_in[8];
  const float* W1l_sc = (const float*)d_in[9];
  const float* b1_sc  = (const float*)d_in[10];
  const float* W1r_sc = (const float*)d_in[11];
  const float* Wlin1_c = (const float*)d_in[12];
  const float* blin1_c = (const float*)d_in[13];
  const float* Wlin1_s = (const float*)d_in[14];
  const float* blin1_s = (const float*)d_in[15];
  const float* W2l_sc = (const float*)d_in[19];
  const float* b2_sc  = (const float*)d_in[20];
  const float* W2r_sc = (const float*)d_in[21];
  const float* Wlin2_c = (const float*)d_in[22];
  const float* blin2_c = (const float*)d_in[23];
  const float* Wch1 = (const float*)d_in[26];
  const float* bch1 = (const float*)d_in[27];
  const float* Wch2 = (const float*)d_in[28];
  const float* bch2 = (const float*)d_in[29];
  const float* Wcat1 = (const float*)d_in[30];
  const float* bcat1 = (const float*)d_in[31];
  const float* Wcat2 = (const float*)d_in[32];
  const float* bcat2 = (const float*)d_in[33];
  const float* Wsk1 = (const float*)d_in[34];
  const float* bsk1 = (const float*)d_in[35];
  const float* Wsk2 = (const float*)d_in[36];
  const float* bsk2 = (const float*)d_in[37];

  const int D = 128;
  const int Nc = in_sizes[0] / D;
  const int Ns = in_sizes[1] / D;
  const int E  = in_sizes[2];
  const int NCAT = in_sizes[33];
  const int NSKU = in_sizes[37];

  const int NTc = (Nc + 127) / 128;
  const int NTs = (Ns + 127) / 128;
  const int Ncp = NTc * 128;
  const int Nsp = NTs * 128;
  const int NCATp = ((NCAT + 127) / 128) * 128;
  const int NSKUp = ((NSKU + 127) / 128) * 128;
  const int ncat_ch = NCATp / 128, nsku_ch = NSKUp / 128;

  // ---- workspace layout ----
  char* wsb = (char*)d_ws;
  size_t o = 0;
  auto alloc = [&](size_t bytes) -> char* {
    char* p = wsb + o;
    o = (o + bytes + 255) & ~(size_t)255;
    return p;
  };
  unsigned short* concat_s = (unsigned short*)alloc((size_t)Nsp * 256 * 2);
  unsigned short* concat_c = (unsigned short*)alloc((size_t)Ncp * 256 * 2);
  unsigned short* h1_s     = (unsigned short*)alloc((size_t)Nsp * 256 * 2);
  unsigned short* big      = (unsigned short*)alloc((size_t)Ncp * 512 * 2);  // concat2
  unsigned short* hidden   = (unsigned short*)alloc((size_t)Ncp * 384 * 2);
  unsigned short* wc1s = (unsigned short*)alloc(256 * 256 * 2);
  float* bc1s = (float*)alloc(256 * 4);
  unsigned short* wc1c = (unsigned short*)alloc(256 * 256 * 2);
  float* bc1c = (float*)alloc(256 * 4);
  unsigned short* wc2c = (unsigned short*)alloc(128 * 512 * 2);
  float* bc2c = (float*)alloc(128 * 4);
  unsigned short* whh  = (unsigned short*)alloc(384 * 128 * 2);
  float* bhh  = (float*)alloc(384 * 4);
  unsigned short* wcat2p = (unsigned short*)alloc((size_t)NCATp * 128 * 2);
  unsigned short* wsk2p  = (unsigned short*)alloc((size_t)NSKUp * 128 * 2);
  int* off   = (int*)alloc((size_t)(Ns + Nc + 1) * 4);
  int* zbase = (int*)alloc((size_t)(2 * (Ns + Nc)) * 4);
  int* cnt = zbase;
  int* cur = zbase + (Ns + Nc);
  int* lst = (int*)alloc((size_t)(2 * E) * 4);
  int* partials = (int*)alloc(1024 * 4);

  float* out_churn = (float*)d_out;
  float* out_cat = out_churn + (size_t)Nc;
  float* out_sku = out_cat + (size_t)Nc * NCAT;
  float* out_emb = out_sku + (size_t)Nc * NSKU;

  hipMemsetAsync(zbase, 0, (size_t)(2 * (Ns + Nc)) * 4, stream);

  // 1. front: prep + l2norm + hist
  const int nl2 = (Nc + Ns + 3) / 4;
  const int nhist = (2 * E + 255) / 256;
  k_front<<<512 + nl2 + nhist, 256, 0, stream>>>(
      W1l_cs, W1r_cs, Wlin1_s, b1_cs, blin1_s,
      W1l_sc, W1r_sc, Wlin1_c, b1_sc, blin1_c,
      W2l_sc, W2r_sc, Wlin2_c, b2_sc, blin2_c,
      Wch1, bch1, Wcat1, bcat1, Wsk1, bsk1, Wcat2, Wsk2,
      wc1s, bc1s, wc1c, bc1c, wc2c, bc2c, whh, bhh, wcat2p, wsk2p,
      NCAT, NCATp, NSKU, NSKUp,
      x_client, x_sku, concat_c, concat_s, Nc, Ns, nl2,
      cs_dst, sc_dst, cnt, E);

  // 2-4. scan
  const int n_nodes = Ns + Nc;
  const int nb = (n_nodes + 1 + 2047) / 2048;
  k_scan1<<<nb, 256, 0, stream>>>(cnt, off, partials, n_nodes, n_nodes + 1);
  k_scan2<<<1, 256, 0, stream>>>(partials, nb);
  k_scan3<<<nb, 256, 0, stream>>>(off, partials, n_nodes + 1);

  // 5. scatter
  k_scatter_both<<<(2 * E + 255) / 256, 256, 0, stream>>>(
      cs_src, cs_dst, sc_src, sc_dst, off, cur, lst, E, Ns);

  // 6. layer-1 aggregation
  k_agg128_both<<<(n_nodes + 3) / 4, 256, 0, stream>>>(
      concat_c, concat_s, off, lst, concat_s, concat_c, Ns, Nc);

  // 7. layer-1 GEMMs (pipelined)
  k_gemm1_both<<<NTs * 2 + NTc * 2, 256, 0, stream>>>(
      concat_s, wc1s, bc1s, h1_s, Ns, NTs * 2,
      concat_c, wc1c, bc1c, big + 256, Nc);

  // 8. layer-2 aggregation (client destinations)
  k_agg_mean256<<<(Nc + 3) / 4, 256, 0, stream>>>(h1_s, off + Ns, lst, big, 512, Nc);

  // 9. emb + hidden (pipelined, 32 KB LDS)
  k_embhid<<<NTc, 256, 0, stream>>>(big, wc2c, bc2c, whh, bhh, out_emb, hidden, Nc);

  // 10. heads + churn (one chunk per block, staged hidden, NT stores)
  k_heads<<<NTc * (ncat_ch + nsku_ch + 1), 256, 0, stream>>>(
      hidden, wcat2p, bcat2, NCAT, ncat_ch, wsk2p, bsk2, NSKU, nsku_ch,
      Wch2, bch2, out_cat, out_sku, out_churn, Nc);
}

// Round 15
// 621.235 us; speedup vs baseline: 1.1482x; 1.1482x over previous
//
#include <hip/hip_runtime.h>
#include <hip/hip_bf16.h>
#include <cstdint>

// ---------------------------------------------------------------------------
// FullModel: hetero-GraphSAGE (2 layers) + 3 MLP heads.
// R15 = R8 verbatim (measured best, 621us). Post-R8 probes all regressed:
//   R9/R11 k_heads grouping -> VGPR spill (+130/+190us)
//   R10 lookback scan -> neutral/harmful
//   R12 0-LDS k_heads -> +19us
//   R13/R14 NT stores -> +92us (scattered 16B NT writes = partial-line HBM RMW)
// All GEMMs: mfma_f32_16x16x32_bf16, fp32 acc, global_load_lds(16B) staging,
// both-sides XOR swizzle (G21). MFMA kernels: __launch_bounds__(256,4).
// ---------------------------------------------------------------------------

typedef __attribute__((ext_vector_type(8))) short bf16x8;
typedef __attribute__((ext_vector_type(4))) float f32x4;

__device__ __forceinline__ float b2f(unsigned short u) {
  return __uint_as_float(((unsigned)u) << 16);
}
__device__ __forceinline__ unsigned short f2b(float f) {
  unsigned u = __float_as_uint(f);
  return (unsigned short)((u + 0x7FFFu + ((u >> 16) & 1u)) >> 16);
}
__device__ __forceinline__ float sigmoidf_(float v) {
  return 1.0f / (1.0f + __expf(-v));
}

__device__ __forceinline__ float waveReduceSum(float v) {
  #pragma unroll
  for (int s = 32; s > 0; s >>= 1) v += __shfl_xor(v, s, 64);
  return v;
}

__device__ __forceinline__ void gload16(const void* g, void* l) {
  __builtin_amdgcn_global_load_lds(
      (const __attribute__((address_space(1))) unsigned int*)g,
      (__attribute__((address_space(3))) unsigned int*)l, 16, 0, 0);
}

// stage a [128 rows][32 k] bf16 tile (linear LDS dest, pre-swizzled source)
__device__ __forceinline__ void stage_tile(const unsigned short* __restrict__ G,
                                           int ld, unsigned short* lds,
                                           int wave, int lane) {
  #pragma unroll
  for (int j = 0; j < 2; ++j) {
    const int p = wave * 128 + j * 64 + lane;
    const int rr = p >> 2;
    const int sl = (p & 3) ^ (rr & 3);
    gload16(G + (size_t)rr * ld + (sl << 3), lds + ((wave * 128 + j * 64) << 3));
  }
}

// stage a [128 rows][128 k] bf16 tile (2048 16B-slots, 8 per thread)
__device__ __forceinline__ void stage_tile128(const unsigned short* __restrict__ G,
                                              int ldg, unsigned short* lds,
                                              int wave, int lane) {
  #pragma unroll
  for (int u = 0; u < 8; ++u) {
    const int base = u * 256 + wave * 64;
    const int p = base + lane;
    const int row = p >> 4;
    const int sl = (p & 15) ^ (row & 7);
    gload16(G + (size_t)row * ldg + (sl << 3), lds + (base << 3));
  }
}

// read an 8-elem bf16 fragment from a staged [rows][32] tile
__device__ __forceinline__ bf16x8 read_frag32(const unsigned short* lds, int row, int kg) {
  const int srd = kg ^ (row & 3);
  return *(const bf16x8*)&lds[row * 32 + (srd << 3)];
}

// [128][128] bf16 LDS tile, 16B-slot swizzle: phys = logical ^ (row&7)
__device__ __forceinline__ bf16x8 read_frag128(const unsigned short* lds, int row, int kslot) {
  const int ps = kslot ^ (row & 7);
  return *(const bf16x8*)&lds[row * 128 + (ps << 3)];
}
__device__ __forceinline__ void write_elem128(unsigned short* lds, int row, int col,
                                              unsigned short v) {
  const int slot = (col >> 3) ^ (row & 7);
  lds[row * 128 + (slot << 3) + (col & 7)] = v;
}

// direct global fragment: 16B at row*ld + koff (L2-hot weights only)
__device__ __forceinline__ bf16x8 gfrag(const unsigned short* __restrict__ G,
                                        int row, int ld, int koff) {
  return *(const bf16x8*)&G[(size_t)row * ld + koff];
}

// ---- k_front: weight prep (blocks [0,512)) + l2norm + histogram ----
__global__ void k_front(
    const float* __restrict__ W1l_cs, const float* __restrict__ W1r_cs,
    const float* __restrict__ Wlin1_s, const float* __restrict__ b1_cs,
    const float* __restrict__ blin1_s,
    const float* __restrict__ W1l_sc, const float* __restrict__ W1r_sc,
    const float* __restrict__ Wlin1_c, const float* __restrict__ b1_sc,
    const float* __restrict__ blin1_c,
    const float* __restrict__ W2l_sc, const float* __restrict__ W2r_sc,
    const float* __restrict__ Wlin2_c, const float* __restrict__ b2_sc,
    const float* __restrict__ blin2_c,
    const float* __restrict__ Wch1, const float* __restrict__ bch1,
    const float* __restrict__ Wcat1, const float* __restrict__ bcat1,
    const float* __restrict__ Wsk1, const float* __restrict__ bsk1,
    const float* __restrict__ Wcat2, const float* __restrict__ Wsk2,
    unsigned short* __restrict__ wc1s, float* __restrict__ bc1s,
    unsigned short* __restrict__ wc1c, float* __restrict__ bc1c,
    unsigned short* __restrict__ wc2c, float* __restrict__ bc2c,
    unsigned short* __restrict__ whh, float* __restrict__ bhh,
    unsigned short* __restrict__ wcat2p, unsigned short* __restrict__ wsk2p,
    int NCAT, int NCATp, int NSKU, int NSKUp,
    const float* __restrict__ xc, const float* __restrict__ xs,
    unsigned short* __restrict__ concat_c, unsigned short* __restrict__ concat_s,
    int Nc, int Ns, int nl2,
    const int* __restrict__ cs_dst, const int* __restrict__ sc_dst,
    int* __restrict__ cnt, int E) {
  const int blk = blockIdx.x;
  if (blk < 512) {
    const int i = blk * 256 + threadIdx.x;
    if (i < 65536) {
      {
        int n = i >> 8, k = i & 255;
        wc1s[i] = f2b(k < 128 ? W1l_cs[n * 128 + k]
                              : W1r_cs[n * 128 + k - 128] + Wlin1_s[n * 128 + k - 128]);
        wc1c[i] = f2b(k < 128 ? W1l_sc[n * 128 + k]
                              : W1r_sc[n * 128 + k - 128] + Wlin1_c[n * 128 + k - 128]);
      }
      {
        int n = i >> 9, k = i & 511;
        wc2c[i] = f2b(k < 256 ? W2l_sc[n * 256 + k]
                              : W2r_sc[n * 256 + k - 256] + Wlin2_c[n * 256 + k - 256]);
      }
    }
    if (i < 256) { bc1s[i] = b1_cs[i] + blin1_s[i]; bc1c[i] = b1_sc[i] + blin1_c[i]; }
    if (i < 128) bc2c[i] = b2_sc[i] + blin2_c[i];
    if (i < 384 * 128) {
      int n = i >> 7, k = i & 127;
      const float* w = n < 128 ? Wch1 : (n < 256 ? Wcat1 : Wsk1);
      whh[i] = f2b(w[(n & 127) * 128 + k]);
    }
    if (i < 384) bhh[i] = i < 128 ? bch1[i] : (i < 256 ? bcat1[i - 128] : bsk1[i - 256]);
    if (i < NCATp * 128) wcat2p[i] = (i >> 7) < NCAT ? f2b(Wcat2[i]) : (unsigned short)0;
    if (i < NSKUp * 128) wsk2p[i] = (i >> 7) < NSKU ? f2b(Wsk2[i]) : (unsigned short)0;
  } else if (blk < 512 + nl2) {
    const int wid = (blk - 512) * 4 + (threadIdx.x >> 6);
    const int lane = threadIdx.x & 63;
    const float* x;
    unsigned short* out;
    if (wid < Nc) {
      x = xc + (size_t)wid * 128;
      out = concat_c + (size_t)wid * 256 + 128;
    } else {
      int w = wid - Nc;
      if (w >= Ns) return;
      x = xs + (size_t)w * 128;
      out = concat_s + (size_t)w * 256 + 128;
    }
    const float2 v = *(const float2*)&x[lane * 2];
    float ss = waveReduceSum(v.x * v.x + v.y * v.y);
    float sc = 1.0f / fmaxf(sqrtf(ss), 1e-12f);
    out[lane * 2] = f2b(v.x * sc);
    out[lane * 2 + 1] = f2b(v.y * sc);
  } else {
    const int i = (blk - 512 - nl2) * 256 + threadIdx.x;
    if (i < E) atomicAdd(&cnt[cs_dst[i]], 1);
    else if (i < 2 * E) atomicAdd(&cnt[Ns + sc_dst[i - E]], 1);
  }
}

// ---- exclusive scan (3-dispatch) ----
__global__ void k_scan1(const int* __restrict__ in, int* __restrict__ out,
                        int* __restrict__ partials, int nin, int nout) {
  __shared__ int sd[256];
  const int tid = threadIdx.x;
  const int base = blockIdx.x * 2048 + tid * 8;
  int v[8];
  int tsum = 0;
  #pragma unroll
  for (int u = 0; u < 8; ++u) {
    int idx = base + u;
    int t = (idx < nin) ? in[idx] : 0;
    v[u] = tsum; tsum += t;
  }
  sd[tid] = tsum;
  __syncthreads();
  for (int offp = 1; offp < 256; offp <<= 1) {
    int t = (tid >= offp) ? sd[tid - offp] : 0;
    __syncthreads();
    sd[tid] += t;
    __syncthreads();
  }
  int texcl = (tid == 0) ? 0 : sd[tid - 1];
  if (tid == 255) partials[blockIdx.x] = sd[255];
  #pragma unroll
  for (int u = 0; u < 8; ++u) {
    int idx = base + u;
    if (idx < nout) out[idx] = v[u] + texcl;
  }
}

__global__ void k_scan2(int* __restrict__ partials, int nb) {
  __shared__ int sd[256];
  const int tid = threadIdx.x;
  int v = (tid < nb) ? partials[tid] : 0;
  sd[tid] = v;
  __syncthreads();
  for (int offp = 1; offp < 256; offp <<= 1) {
    int t = (tid >= offp) ? sd[tid - offp] : 0;
    __syncthreads();
    sd[tid] += t;
    __syncthreads();
  }
  if (tid < nb) partials[tid] = (tid == 0) ? 0 : sd[tid - 1];
}

__global__ void k_scan3(int* __restrict__ out, const int* __restrict__ partials, int nout) {
  int add = partials[blockIdx.x];
  int base = blockIdx.x * 2048 + threadIdx.x * 8;
  #pragma unroll
  for (int u = 0; u < 8; ++u) {
    int idx = base + u;
    if (idx < nout) out[idx] += add;
  }
}

// ---- scatter both edge sets into one adjacency array ----
__global__ void k_scatter_both(const int* __restrict__ cs_src, const int* __restrict__ cs_dst,
                               const int* __restrict__ sc_src, const int* __restrict__ sc_dst,
                               const int* __restrict__ off, int* __restrict__ cur,
                               int* __restrict__ lst, int E, int Ns) {
  int i = blockIdx.x * blockDim.x + threadIdx.x;
  if (i >= 2 * E) return;
  int d, s;
  if (i < E) { d = cs_dst[i]; s = cs_src[i]; }
  else { d = Ns + sc_dst[i - E]; s = sc_src[i - E]; }
  int p = atomicAdd(&cur[d], 1);
  lst[off[d] + p] = s;
}

// ---- layer-1 mean aggregation, both directions, depth-4 unrolled ----
__global__ void k_agg128_both(const unsigned short* __restrict__ concat_c,
                              const unsigned short* __restrict__ concat_s,
                              const int* __restrict__ off, const int* __restrict__ lst,
                              unsigned short* __restrict__ out_s,
                              unsigned short* __restrict__ out_c, int Ns, int Nc) {
  int wid = (blockIdx.x * blockDim.x + threadIdx.x) >> 6;
  int lane = threadIdx.x & 63;
  const unsigned short* feat;
  unsigned short* out;
  int s, e;
  if (wid < Ns) {
    s = off[wid]; e = off[wid + 1];
    feat = concat_c; out = out_s + (size_t)wid * 256;
  } else {
    int w = wid - Ns;
    if (w >= Nc) return;
    s = off[Ns + w]; e = off[Ns + w + 1];
    feat = concat_s; out = out_c + (size_t)w * 256;
  }
  float ax0 = 0.f, ay0 = 0.f, ax1 = 0.f, ay1 = 0.f;
  float ax2 = 0.f, ay2 = 0.f, ax3 = 0.f, ay3 = 0.f;
  int i = s;
  for (; i + 4 <= e; i += 4) {
    int r0 = lst[i], r1 = lst[i + 1], r2 = lst[i + 2], r3 = lst[i + 3];
    unsigned v0 = *(const unsigned*)&feat[(size_t)r0 * 256 + 128 + lane * 2];
    unsigned v1 = *(const unsigned*)&feat[(size_t)r1 * 256 + 128 + lane * 2];
    unsigned v2 = *(const unsigned*)&feat[(size_t)r2 * 256 + 128 + lane * 2];
    unsigned v3 = *(const unsigned*)&feat[(size_t)r3 * 256 + 128 + lane * 2];
    ax0 += b2f((unsigned short)(v0 & 0xFFFF)); ay0 += b2f((unsigned short)(v0 >> 16));
    ax1 += b2f((unsigned short)(v1 & 0xFFFF)); ay1 += b2f((unsigned short)(v1 >> 16));
    ax2 += b2f((unsigned short)(v2 & 0xFFFF)); ay2 += b2f((unsigned short)(v2 >> 16));
    ax3 += b2f((unsigned short)(v3 & 0xFFFF)); ay3 += b2f((unsigned short)(v3 >> 16));
  }
  for (; i < e; ++i) {
    int r0 = lst[i];
    unsigned v0 = *(const unsigned*)&feat[(size_t)r0 * 256 + 128 + lane * 2];
    ax0 += b2f((unsigned short)(v0 & 0xFFFF)); ay0 += b2f((unsigned short)(v0 >> 16));
  }
  float inv = 1.0f / (float)((e - s) > 0 ? (e - s) : 1);
  out[lane * 2] = f2b((ax0 + ax1 + ax2 + ax3) * inv);
  out[lane * 2 + 1] = f2b((ay0 + ay1 + ay2 + ay3) * inv);
}

// ---- layer-2 mean aggregation (256-wide), depth-4 unrolled ----
__global__ void k_agg_mean256(const unsigned short* __restrict__ feat,
                              const int* __restrict__ off, const int* __restrict__ lst,
                              unsigned short* __restrict__ out, int ostride, int n) {
  int wid = (blockIdx.x * blockDim.x + threadIdx.x) >> 6;
  int lane = threadIdx.x & 63;
  if (wid >= n) return;
  int s = off[wid], e = off[wid + 1];
  float a[4] = {0.f, 0.f, 0.f, 0.f};
  float b[4] = {0.f, 0.f, 0.f, 0.f};
  float c[4] = {0.f, 0.f, 0.f, 0.f};
  float d[4] = {0.f, 0.f, 0.f, 0.f};
  int i = s;
  for (; i + 4 <= e; i += 4) {
    int r0 = lst[i], r1 = lst[i + 1], r2 = lst[i + 2], r3 = lst[i + 3];
    uint2 v0 = *(const uint2*)&feat[(size_t)r0 * 256 + lane * 4];
    uint2 v1 = *(const uint2*)&feat[(size_t)r1 * 256 + lane * 4];
    uint2 v2 = *(const uint2*)&feat[(size_t)r2 * 256 + lane * 4];
    uint2 v3 = *(const uint2*)&feat[(size_t)r3 * 256 + lane * 4];
    a[0] += b2f((unsigned short)(v0.x & 0xFFFF)); a[1] += b2f((unsigned short)(v0.x >> 16));
    a[2] += b2f((unsigned short)(v0.y & 0xFFFF)); a[3] += b2f((unsigned short)(v0.y >> 16));
    b[0] += b2f((unsigned short)(v1.x & 0xFFFF)); b[1] += b2f((unsigned short)(v1.x >> 16));
    b[2] += b2f((unsigned short)(v1.y & 0xFFFF)); b[3] += b2f((unsigned short)(v1.y >> 16));
    c[0] += b2f((unsigned short)(v2.x & 0xFFFF)); c[1] += b2f((unsigned short)(v2.x >> 16));
    c[2] += b2f((unsigned short)(v2.y & 0xFFFF)); c[3] += b2f((unsigned short)(v2.y >> 16));
    d[0] += b2f((unsigned short)(v3.x & 0xFFFF)); d[1] += b2f((unsigned short)(v3.x >> 16));
    d[2] += b2f((unsigned short)(v3.y & 0xFFFF)); d[3] += b2f((unsigned short)(v3.y >> 16));
  }
  for (; i < e; ++i) {
    int r0 = lst[i];
    uint2 v0 = *(const uint2*)&feat[(size_t)r0 * 256 + lane * 4];
    a[0] += b2f((unsigned short)(v0.x & 0xFFFF)); a[1] += b2f((unsigned short)(v0.x >> 16));
    a[2] += b2f((unsigned short)(v0.y & 0xFFFF)); a[3] += b2f((unsigned short)(v0.y >> 16));
  }
  float inv = 1.0f / (float)((e - s) > 0 ? (e - s) : 1);
  unsigned short* o = &out[(size_t)wid * ostride + lane * 4];
  o[0] = f2b((a[0] + b[0] + c[0] + d[0]) * inv);
  o[1] = f2b((a[1] + b[1] + c[1] + d[1]) * inv);
  o[2] = f2b((a[2] + b[2] + c[2] + d[2]) * inv);
  o[3] = f2b((a[3] + b[3] + c[3] + d[3]) * inv);
}

// ---- layer-1 GEMMs, both node types, 2-phase pipelined staging ----
__global__ __launch_bounds__(256, 4) void k_gemm1_both(
    const unsigned short* __restrict__ As_g, const unsigned short* __restrict__ Ws_g,
    const float* __restrict__ bs_g, unsigned short* __restrict__ Cs_g, int Ms, int NTs2,
    const unsigned short* __restrict__ Ac_g, const unsigned short* __restrict__ Wc_g,
    const float* __restrict__ bc_g, unsigned short* __restrict__ Cc_g, int Mc) {
  __shared__ __align__(16) unsigned short As[8192];  // dbuf 2x4096
  __shared__ __align__(16) unsigned short Bs[8192];
  const int nwg = gridDim.x, orig = blockIdx.x;
  const int q8 = nwg >> 3, r8 = nwg & 7;
  const int xcd = orig & 7, cidx = orig >> 3;
  int wg = (xcd < r8 ? xcd * (q8 + 1) : r8 * (q8 + 1) + (xcd - r8) * q8) + cidx;

  const unsigned short *A, *W;
  const float* bias;
  unsigned short* C;
  int M, ldc;
  if (wg < NTs2) { A = As_g; W = Ws_g; bias = bs_g; C = Cs_g; M = Ms; ldc = 256; }
  else { wg -= NTs2; A = Ac_g; W = Wc_g; bias = bc_g; C = Cc_g; M = Mc; ldc = 512; }
  const int bm = (wg >> 1) * 128, bn = (wg & 1) * 128;

  const int tid = threadIdx.x, lane = tid & 63, wave = tid >> 6;
  const int wm = (wave >> 1) << 6, wn = (wave & 1) << 6;
  const int l15 = lane & 15, l4 = lane >> 4;

  const unsigned short* Abase = A + (size_t)bm * 256;
  const unsigned short* Wbase = W + (size_t)bn * 256;

  f32x4 acc[4][4] = {};
  stage_tile(Abase, 256, As, wave, lane);
  stage_tile(Wbase, 256, Bs, wave, lane);
  __syncthreads();
  int cur = 0;
  for (int t = 0; t < 8; ++t) {
    if (t < 7) {
      stage_tile(Abase + (t + 1) * 32, 256, As + ((cur ^ 1) << 12), wave, lane);
      stage_tile(Wbase + (t + 1) * 32, 256, Bs + ((cur ^ 1) << 12), wave, lane);
    }
    const unsigned short* Ac = As + (cur << 12);
    const unsigned short* Bc = Bs + (cur << 12);
    bf16x8 af[4], bfr[4];
    #pragma unroll
    for (int i = 0; i < 4; ++i) {
      af[i] = read_frag32(Ac, wm + i * 16 + l15, l4);
      bfr[i] = read_frag32(Bc, wn + i * 16 + l15, l4);
    }
    #pragma unroll
    for (int i = 0; i < 4; ++i)
      #pragma unroll
      for (int j = 0; j < 4; ++j)
        acc[i][j] = __builtin_amdgcn_mfma_f32_16x16x32_bf16(af[i], bfr[j], acc[i][j], 0, 0, 0);
    __syncthreads();
    cur ^= 1;
  }
  #pragma unroll
  for (int j = 0; j < 4; ++j) {
    int col = bn + wn + j * 16 + l15;
    float bj = bias[col];
    #pragma unroll
    for (int i = 0; i < 4; ++i) {
      int r0 = bm + wm + i * 16 + (l4 << 2);
      #pragma unroll
      for (int q = 0; q < 4; ++q) {
        int row = r0 + q;
        if (row < M) C[(size_t)row * ldc + col] = f2b(fmaxf(acc[i][j][q] + bj, 0.0f));
      }
    }
  }
}

// ---- k_embhid: emb (K=512, pipelined, 32 KB aliased LDS) -> out_emb fp32 +
//      embT LDS; then 12 barrier-free steps (Whh direct) -> hidden[Ncp][384] ----
__global__ __launch_bounds__(256, 4) void k_embhid(
    const unsigned short* __restrict__ A2, const unsigned short* __restrict__ W2,
    const float* __restrict__ b2,
    const unsigned short* __restrict__ Whh, const float* __restrict__ bhh,
    float* __restrict__ out_emb, unsigned short* __restrict__ hidden, int M) {
  __shared__ __align__(16) unsigned short smem[16384];  // 32 KB total
  unsigned short* As = smem;          // dbuf 2x4096 ushort (16 KB)
  unsigned short* Bs = smem + 8192;   // dbuf 2x4096 ushort (16 KB)
  unsigned short* embT = smem;        // [128][128] alias, valid after emb loop

  const int bm = blockIdx.x * 128;
  const int tid = threadIdx.x, lane = tid & 63, wave = tid >> 6;
  const int wm = (wave >> 1) << 6, wn = (wave & 1) << 6;
  const int l15 = lane & 15, l4 = lane >> 4;

  f32x4 acc[4][4] = {};
  {  // emb: K=512, 16 pipelined steps
    const unsigned short* Abase = A2 + (size_t)bm * 512;
    stage_tile(Abase, 512, As, wave, lane);
    stage_tile(W2, 512, Bs, wave, lane);
    __syncthreads();
    int cur = 0;
    for (int t = 0; t < 16; ++t) {
      if (t < 15) {
        stage_tile(Abase + (t + 1) * 32, 512, As + ((cur ^ 1) << 12), wave, lane);
        stage_tile(W2 + (t + 1) * 32, 512, Bs + ((cur ^ 1) << 12), wave, lane);
      }
      const unsigned short* Ac = As + (cur << 12);
      const unsigned short* Bc = Bs + (cur << 12);
      bf16x8 af[4], bfr[4];
      #pragma unroll
      for (int i = 0; i < 4; ++i) {
        af[i] = read_frag32(Ac, wm + i * 16 + l15, l4);
        bfr[i] = read_frag32(Bc, wn + i * 16 + l15, l4);
      }
      #pragma unroll
      for (int i = 0; i < 4; ++i)
        #pragma unroll
        for (int j = 0; j < 4; ++j)
          acc[i][j] = __builtin_amdgcn_mfma_f32_16x16x32_bf16(af[i], bfr[j], acc[i][j], 0, 0, 0);
      __syncthreads();  // after final iter: all LDS reads done -> embT alias safe
      cur ^= 1;
    }
    #pragma unroll
    for (int j = 0; j < 4; ++j) {
      int col = wn + j * 16 + l15;
      float bj = b2[col];
      #pragma unroll
      for (int i = 0; i < 4; ++i) {
        int r0 = wm + i * 16 + (l4 << 2);
        #pragma unroll
        for (int q = 0; q < 4; ++q) {
          float v = acc[i][j][q] + bj;
          int rl = r0 + q;
          if (bm + rl < M) out_emb[(size_t)(bm + rl) * 128 + col] = v;
          write_elem128(embT, rl, col, f2b(v));
        }
      }
    }
  }
  __syncthreads();  // embT visible to all waves

  // hidden: 12 flat steps (hc = s>>2, tt = s&3), Whh direct-global, no barriers
  f32x4 hacc[4][4] = {};
  for (int s = 0; s < 12; ++s) {
    const int hc = s >> 2, tt = s & 3;
    bf16x8 af[4], bfr[4];
    const int kslot = tt * 4 + l4;
    #pragma unroll
    for (int i = 0; i < 4; ++i) {
      af[i] = read_frag128(embT, wm + i * 16 + l15, kslot);
      bfr[i] = gfrag(Whh, hc * 128 + wn + i * 16 + l15, 128, tt * 32 + l4 * 8);
    }
    #pragma unroll
    for (int i = 0; i < 4; ++i)
      #pragma unroll
      for (int j = 0; j < 4; ++j)
        hacc[i][j] = __builtin_amdgcn_mfma_f32_16x16x32_bf16(af[i], bfr[j], hacc[i][j], 0, 0, 0);
    if (tt == 3) {  // epilogue for this chunk
      #pragma unroll
      for (int j = 0; j < 4; ++j) {
        int col = wn + j * 16 + l15;
        float bj = bhh[hc * 128 + col];
        #pragma unroll
        for (int i = 0; i < 4; ++i) {
          int r0 = wm + i * 16 + (l4 << 2);
          #pragma unroll
          for (int q = 0; q < 4; ++q) {
            hidden[(size_t)(bm + r0 + q) * 384 + hc * 128 + col] =
                f2b(fmaxf(hacc[i][j][q] + bj, 0.0f));
            hacc[i][j][q] = 0.0f;
          }
        }
      }
    }
  }
}

// ---- k_heads: one 128x128 chunk per block; hidden staged in LDS (32 KB),
//      W chunk direct (L2-hot); churn role last. float4 output stores. ----
__global__ __launch_bounds__(256, 4) void k_heads(
    const unsigned short* __restrict__ hidden,
    const unsigned short* __restrict__ Wcat, const float* __restrict__ bcat, int NCAT,
    int ncat_ch,
    const unsigned short* __restrict__ Wsku, const float* __restrict__ bsku, int NSKU,
    int nsku_ch,
    const float* __restrict__ wch2, const float* __restrict__ bch2,
    float* __restrict__ out_cat, float* __restrict__ out_sku,
    float* __restrict__ out_churn, int M) {
  __shared__ __align__(16) unsigned short Bh[16384];  // hidden tile [128][128]

  const int nwg = gridDim.x, orig = blockIdx.x;
  const int q8 = nwg >> 3, r8 = nwg & 7;
  const int xcd = orig & 7, cidx = orig >> 3;
  const int wg = (xcd < r8 ? xcd * (q8 + 1) : r8 * (q8 + 1) + (xcd - r8) * q8) + cidx;

  const int nroles = ncat_ch + nsku_ch + 1;
  const int bt = wg / nroles;
  const int c = wg % nroles;
  const int bm = bt * 128;

  const int tid = threadIdx.x, lane = tid & 63, wave = tid >> 6;

  if (c == ncat_ch + nsku_ch) {
    const float2 ww = *(const float2*)&wch2[lane * 2];
    const float bb = bch2[0];
    for (int r = wave * 32; r < wave * 32 + 32; ++r) {
      const int row = bm + r;
      if (row >= M) break;
      unsigned v = *(const unsigned*)&hidden[(size_t)row * 384 + lane * 2];
      float sum = waveReduceSum(b2f((unsigned short)(v & 0xFFFF)) * ww.x +
                                b2f((unsigned short)(v >> 16)) * ww.y);
      if (lane == 0) out_churn[row] = sigmoidf_(sum + bb);
    }
    return;
  }

  const unsigned short* Wh;
  const float* bh;
  float* oh;
  int Nh, cc, hoff;
  if (c < ncat_ch) { Wh = Wcat; bh = bcat; oh = out_cat; Nh = NCAT; cc = c; hoff = 128; }
  else { Wh = Wsku; bh = bsku; oh = out_sku; Nh = NSKU; cc = c - ncat_ch; hoff = 256; }

  const int wm = (wave >> 1) << 6, wn = (wave & 1) << 6;
  const int l15 = lane & 15, l4 = lane >> 4;

  stage_tile128(hidden + (size_t)bm * 384 + hoff, 384, Bh, wave, lane);
  __syncthreads();

  f32x4 acc[4][4] = {};
  #pragma unroll
  for (int ks = 0; ks < 4; ++ks) {
    bf16x8 af[4], bfr[4];
    #pragma unroll
    for (int i = 0; i < 4; ++i) {
      af[i] = gfrag(Wh, cc * 128 + wm + i * 16 + l15, 128, ks * 32 + l4 * 8);
      bfr[i] = read_frag128(Bh, wn + i * 16 + l15, ks * 4 + l4);
    }
    #pragma unroll
    for (int i = 0; i < 4; ++i)
      #pragma unroll
      for (int j = 0; j < 4; ++j)
        acc[i][j] = __builtin_amdgcn_mfma_f32_16x16x32_bf16(af[i], bfr[j], acc[i][j], 0, 0, 0);
  }

  // transposed epilogue: D[a=headcol][b=client row]
  #pragma unroll
  for (int i = 0; i < 4; ++i) {
    const int n0 = cc * 128 + wm + i * 16 + (l4 << 2);
    if (n0 < Nh) {  // Nh % 4 == 0 -> whole quad valid
      const float4 bv = *(const float4*)&bh[n0];
      #pragma unroll
      for (int j = 0; j < 4; ++j) {
        const int m = wn + j * 16 + l15;
        if (bm + m < M) {
          float4 ov;
          ov.x = sigmoidf_(acc[i][j][0] + bv.x);
          ov.y = sigmoidf_(acc[i][j][1] + bv.y);
          ov.z = sigmoidf_(acc[i][j][2] + bv.z);
          ov.w = sigmoidf_(acc[i][j][3] + bv.w);
          *(float4*)&oh[(size_t)(bm + m) * Nh + n0] = ov;
        }
      }
    }
  }
}

extern "C" void kernel_launch(void* const* d_in, const int* in_sizes, int n_in,
                              void* d_out, int out_size, void* d_ws, size_t ws_size,
                              hipStream_t stream) {
  const float* x_client = (const float*)d_in[0];
  const float* x_sku    = (const float*)d_in[1];
  const int* cs_src = (const int*)d_in[2];
  const int* cs_dst = (const int*)d_in[3];
  const int* sc_src = (const int*)d_in[4];
  const int* sc_dst = (const int*)d_in[5];
  const float* W1l_cs = (const float*)d_in[6];
  const float* b1_cs  = (const float*)d_in[7];
  const float* W1r_cs = (const float*)d_in[8];
  const float* W1l_sc = (const float*)d_in[9];
  const float* b1_sc  = (const float*)d_in[10];
  const float* W1r_sc = (const float*)d_in[11];
  const float* Wlin1_c = (const float*)d_in[12];
  const float* blin1_c = (const float*)d_in[13];
  const float* Wlin1_s = (const float*)d_in[14];
  const float* blin1_s = (const float*)d_in[15];
  const float* W2l_sc = (const float*)d_in[19];
  const float* b2_sc  = (const float*)d_in[20];
  const float* W2r_sc = (const float*)d_in[21];
  const float* Wlin2_c = (const float*)d_in[22];
  const float* blin2_c = (const float*)d_in[23];
  const float* Wch1 = (const float*)d_in[26];
  const float* bch1 = (const float*)d_in[27];
  const float* Wch2 = (const float*)d_in[28];
  const float* bch2 = (const float*)d_in[29];
  const float* Wcat1 = (const float*)d_in[30];
  const float* bcat1 = (const float*)d_in[31];
  const float* Wcat2 = (const float*)d_in[32];
  const float* bcat2 = (const float*)d_in[33];
  const float* Wsk1 = (const float*)d_in[34];
  const float* bsk1 = (const float*)d_in[35];
  const float* Wsk2 = (const float*)d_in[36];
  const float* bsk2 = (const float*)d_in[37];

  const int D = 128;
  const int Nc = in_sizes[0] / D;
  const int Ns = in_sizes[1] / D;
  const int E  = in_sizes[2];
  const int NCAT = in_sizes[33];
  const int NSKU = in_sizes[37];

  const int NTc = (Nc + 127) / 128;
  const int NTs = (Ns + 127) / 128;
  const int Ncp = NTc * 128;
  const int Nsp = NTs * 128;
  const int NCATp = ((NCAT + 127) / 128) * 128;
  const int NSKUp = ((NSKU + 127) / 128) * 128;
  const int ncat_ch = NCATp / 128, nsku_ch = NSKUp / 128;

  // ---- workspace layout ----
  char* wsb = (char*)d_ws;
  size_t o = 0;
  auto alloc = [&](size_t bytes) -> char* {
    char* p = wsb + o;
    o = (o + bytes + 255) & ~(size_t)255;
    return p;
  };
  unsigned short* concat_s = (unsigned short*)alloc((size_t)Nsp * 256 * 2);
  unsigned short* concat_c = (unsigned short*)alloc((size_t)Ncp * 256 * 2);
  unsigned short* h1_s     = (unsigned short*)alloc((size_t)Nsp * 256 * 2);
  unsigned short* big      = (unsigned short*)alloc((size_t)Ncp * 512 * 2);  // concat2
  unsigned short* hidden   = (unsigned short*)alloc((size_t)Ncp * 384 * 2);
  unsigned short* wc1s = (unsigned short*)alloc(256 * 256 * 2);
  float* bc1s = (float*)alloc(256 * 4);
  unsigned short* wc1c = (unsigned short*)alloc(256 * 256 * 2);
  float* bc1c = (float*)alloc(256 * 4);
  unsigned short* wc2c = (unsigned short*)alloc(128 * 512 * 2);
  float* bc2c = (float*)alloc(128 * 4);
  unsigned short* whh  = (unsigned short*)alloc(384 * 128 * 2);
  float* bhh  = (float*)alloc(384 * 4);
  unsigned short* wcat2p = (unsigned short*)alloc((size_t)NCATp * 128 * 2);
  unsigned short* wsk2p  = (unsigned short*)alloc((size_t)NSKUp * 128 * 2);
  int* off   = (int*)alloc((size_t)(Ns + Nc + 1) * 4);
  int* zbase = (int*)alloc((size_t)(2 * (Ns + Nc)) * 4);
  int* cnt = zbase;
  int* cur = zbase + (Ns + Nc);
  int* lst = (int*)alloc((size_t)(2 * E) * 4);
  int* partials = (int*)alloc(1024 * 4);

  float* out_churn = (float*)d_out;
  float* out_cat = out_churn + (size_t)Nc;
  float* out_sku = out_cat + (size_t)Nc * NCAT;
  float* out_emb = out_sku + (size_t)Nc * NSKU;

  hipMemsetAsync(zbase, 0, (size_t)(2 * (Ns + Nc)) * 4, stream);

  // 1. front: prep + l2norm + hist
  const int nl2 = (Nc + Ns + 3) / 4;
  const int nhist = (2 * E + 255) / 256;
  k_front<<<512 + nl2 + nhist, 256, 0, stream>>>(
      W1l_cs, W1r_cs, Wlin1_s, b1_cs, blin1_s,
      W1l_sc, W1r_sc, Wlin1_c, b1_sc, blin1_c,
      W2l_sc, W2r_sc, Wlin2_c, b2_sc, blin2_c,
      Wch1, bch1, Wcat1, bcat1, Wsk1, bsk1, Wcat2, Wsk2,
      wc1s, bc1s, wc1c, bc1c, wc2c, bc2c, whh, bhh, wcat2p, wsk2p,
      NCAT, NCATp, NSKU, NSKUp,
      x_client, x_sku, concat_c, concat_s, Nc, Ns, nl2,
      cs_dst, sc_dst, cnt, E);

  // 2-4. scan
  const int n_nodes = Ns + Nc;
  const int nb = (n_nodes + 1 + 2047) / 2048;
  k_scan1<<<nb, 256, 0, stream>>>(cnt, off, partials, n_nodes, n_nodes + 1);
  k_scan2<<<1, 256, 0, stream>>>(partials, nb);
  k_scan3<<<nb, 256, 0, stream>>>(off, partials, n_nodes + 1);

  // 5. scatter
  k_scatter_both<<<(2 * E + 255) / 256, 256, 0, stream>>>(
      cs_src, cs_dst, sc_src, sc_dst, off, cur, lst, E, Ns);

  // 6. layer-1 aggregation
  k_agg128_both<<<(n_nodes + 3) / 4, 256, 0, stream>>>(
      concat_c, concat_s, off, lst, concat_s, concat_c, Ns, Nc);

  // 7. layer-1 GEMMs (pipelined)
  k_gemm1_both<<<NTs * 2 + NTc * 2, 256, 0, stream>>>(
      concat_s, wc1s, bc1s, h1_s, Ns, NTs * 2,
      concat_c, wc1c, bc1c, big + 256, Nc);

  // 8. layer-2 aggregation (client destinations)
  k_agg_mean256<<<(Nc + 3) / 4, 256, 0, stream>>>(h1_s, off + Ns, lst, big, 512, Nc);

  // 9. emb + hidden (pipelined, 32 KB LDS)
  k_embhid<<<NTc, 256, 0, stream>>>(big, wc2c, bc2c, whh, bhh, out_emb, hidden, Nc);

  // 10. heads + churn (one chunk per block, staged hidden)
  k_heads<<<NTc * (ncat_ch + nsku_ch + 1), 256, 0, stream>>>(
      hidden, wcat2p, bcat2, NCAT, ncat_ch, wsk2p, bsk2, NSKU, nsku_ch,
      Wch2, bch2, out_cat, out_sku, out_churn, Nc);
}